// Round 1
// baseline (46.738 us; speedup 1.0000x reference)
//
#include <hip/hip_runtime.h>
#include <math.h>

// Problem constants (reference is fixed-shape).
#define B_ 16
#define N_ 2048
#define D_ 128
#define NT 16            // N/128 tiles per batch

typedef __attribute__((ext_vector_type(8))) short bf16x8;   // 8 bf16 = 4 VGPRs
typedef __attribute__((ext_vector_type(4))) float f32x4;

__device__ __forceinline__ unsigned short f2bf(float f) {
    // round-to-nearest-even fp32 -> bf16 (inputs are finite Gaussians; no NaN path)
    unsigned u = __float_as_uint(f);
    u += 0x7FFFu + ((u >> 16) & 1u);
    return (unsigned short)(u >> 16);
}

// ---------------------------------------------------------------------------
// K1: fp32 -> bf16 (pre-swizzled layout) + fp32 squared norms.
// Swizzle: element d of row r stored at index d ^ ((r&7)<<3)  (16B-chunk XOR),
// so a later LINEAR global->LDS copy yields a bank-conflict-free LDS layout
// when read back with the same XOR.
// One wave per row; lane handles 2 elements.
// ---------------------------------------------------------------------------
__global__ __launch_bounds__(256) void prep_kernel(
        const float* __restrict__ X, unsigned short* __restrict__ Xs,
        float* __restrict__ sqn) {
    int row = blockIdx.x * 4 + (threadIdx.x >> 6);
    int ln  = threadIdx.x & 63;
    const float* src = X + (size_t)row * D_;
    float2 v = *(const float2*)(src + ln * 2);
    unsigned short h0 = f2bf(v.x), h1 = f2bf(v.y);
    float f0 = __uint_as_float((unsigned)h0 << 16);
    float f1 = __uint_as_float((unsigned)h1 << 16);
    float s = f0 * f0 + f1 * f1;
    #pragma unroll
    for (int o = 32; o; o >>= 1) s += __shfl_xor(s, o, 64);
    int r7  = row & 7;               // row within 128-tile has same low bits
    int d   = ln * 2;
    int dsw = d ^ (r7 << 3);         // XOR affects bits>=3 only; pair stays intact
    unsigned pack = (unsigned)h0 | ((unsigned)h1 << 16);
    *(unsigned*)(Xs + (size_t)row * D_ + dsw) = pack;
    if (ln == 0) sqn[row] = s;
}

// ---------------------------------------------------------------------------
// K2: fused Gram + row-min.  One WG (4 waves, 256 thr) per 128-row i-tile.
// A-fragments (this wave's 32 rows, all of K=128) live in registers for the
// whole j-sweep.  Xj tiles are double-buffered in LDS via global_load_lds
// (linear copy of the pre-swizzled global layout).
// Tracks rmin = min_j (n_j - 2*g_ij); nnd = sqrt(max(n_i + rmin, 0)).
// ---------------------------------------------------------------------------
__device__ __forceinline__ void stage_tile(const unsigned short* gsrc,
                                           unsigned short* lds, int wv, int ln) {
    // 32 KB tile, 4 waves: each wave copies 8 KB = 8 x (64 lanes x 16 B).
    const char* g = (const char*)gsrc + wv * 8192 + ln * 16;
    char*       l = (char*)lds + wv * 8192;          // wave-uniform LDS base
    #pragma unroll
    for (int i = 0; i < 8; ++i) {
        __builtin_amdgcn_global_load_lds(
            (const __attribute__((address_space(1))) unsigned int*)(g + i * 1024),
            (__attribute__((address_space(3))) unsigned int*)(l + i * 1024),
            16, 0, 0);
    }
}

__global__ __launch_bounds__(256) void nnd_kernel(
        const unsigned short* __restrict__ Xs, const float* __restrict__ sqn,
        float* __restrict__ nnd) {
    __shared__ unsigned short Xj[2][128 * D_];   // 2 x 32 KB

    // XCD-chunked remap: default XCD assignment is (blockIdx % 8); give each
    // XCD 32 consecutive work ids -> only 2 batches per XCD L2.
    int wg  = (int)blockIdx.x;
    int id  = (wg & 7) * 32 + (wg >> 3);
    int b   = id >> 4;
    int it  = id & 15;

    int tid = threadIdx.x, wv = tid >> 6, ln = tid & 63;
    const unsigned short* Xb  = Xs  + (size_t)b * N_ * D_;
    const float*          sqb = sqn + b * N_;

    int RL = wv * 32;                 // this wave's row base within the i-tile
    int lr = ln & 15;                 // fragment row/col lane index
    int kg = (ln >> 4) * 8;           // fragment k-group offset

    // Load A fragments from global (pre-swizzled layout), keep in registers.
    bf16x8 Af[2][4];
    #pragma unroll
    for (int m = 0; m < 2; ++m) {
        int r  = RL + m * 16 + lr;                    // local row 0..127
        const unsigned short* rp = Xb + (size_t)(it * 128 + r) * D_;
        int sw = (r & 7) << 3;
        #pragma unroll
        for (int ks = 0; ks < 4; ++ks) {
            int k = ks * 32 + kg;
            Af[m][ks] = *(const bf16x8*)(rp + (k ^ sw));
        }
    }

    float rmin[8];
    #pragma unroll
    for (int q = 0; q < 8; ++q) rmin[q] = 1e30f;

    const f32x4 zero4 = {0.f, 0.f, 0.f, 0.f};

    stage_tile(Xb, Xj[0], wv, ln);
    __syncthreads();

    for (int jt = 0; jt < NT; ++jt) {
        int cur = jt & 1;
        if (jt + 1 < NT)
            stage_tile(Xb + (size_t)(jt + 1) * 128 * D_, Xj[cur ^ 1], wv, ln);

        const unsigned short* L = &Xj[cur][0];
        f32x4 acc[2][8];
        #pragma unroll
        for (int ks = 0; ks < 4; ++ks) {
            bf16x8 Bf[8];
            int k = ks * 32 + kg;
            #pragma unroll
            for (int n = 0; n < 8; ++n) {
                int c = n * 16 + lr;                  // Xj row == output col
                Bf[n] = *(const bf16x8*)(L + c * D_ + (k ^ ((c & 7) << 3)));
            }
            #pragma unroll
            for (int m = 0; m < 2; ++m)
                #pragma unroll
                for (int n = 0; n < 8; ++n)
                    acc[m][n] = __builtin_amdgcn_mfma_f32_16x16x32_bf16(
                        Af[m][ks], Bf[n], ks ? acc[m][n] : zero4, 0, 0, 0);
        }

        // Epilogue: fold min_j (n_j - 2 g).  C/D layout: col = lane&15,
        // row = (lane>>4)*4 + reg  [m89/m91].
        float nj[8];
        #pragma unroll
        for (int n = 0; n < 8; ++n) nj[n] = sqb[jt * 128 + n * 16 + lr];

        if (it != jt) {
            #pragma unroll
            for (int m = 0; m < 2; ++m)
                #pragma unroll
                for (int n = 0; n < 8; ++n)
                    #pragma unroll
                    for (int r = 0; r < 4; ++r)
                        rmin[m * 4 + r] = fminf(rmin[m * 4 + r],
                                                fmaf(-2.f, acc[m][n][r], nj[n]));
        } else {
            #pragma unroll
            for (int m = 0; m < 2; ++m)
                #pragma unroll
                for (int n = 0; n < 8; ++n)
                    #pragma unroll
                    for (int r = 0; r < 4; ++r) {
                        int ir = RL + m * 16 + (ln >> 4) * 4 + r;
                        int jc = n * 16 + lr;
                        float t = (ir == jc) ? 1e30f
                                             : fmaf(-2.f, acc[m][n][r], nj[n]);
                        rmin[m * 4 + r] = fminf(rmin[m * 4 + r], t);
                    }
        }
        __syncthreads();
    }

    // Min across the 16 column-lanes of each row group.
    #pragma unroll
    for (int o = 1; o < 16; o <<= 1)
        #pragma unroll
        for (int q = 0; q < 8; ++q)
            rmin[q] = fminf(rmin[q], __shfl_xor(rmin[q], o, 64));

    if (lr == 0) {
        #pragma unroll
        for (int m = 0; m < 2; ++m)
            #pragma unroll
            for (int r = 0; r < 4; ++r) {
                int row  = it * 128 + RL + m * 16 + (ln >> 4) * 4 + r;
                float ni = sqb[row];
                float d2 = ni + rmin[m * 4 + r];
                nnd[b * N_ + row] = sqrtf(fmaxf(d2, 0.f));
            }
    }
}

// ---------------------------------------------------------------------------
// K3: mean / unbiased std / CV over all 32768 nnd values, in double.
// ---------------------------------------------------------------------------
__global__ __launch_bounds__(1024) void finalize_kernel(
        const float* __restrict__ nnd, float* __restrict__ out) {
    const int M = B_ * N_;
    double s1 = 0.0, s2 = 0.0;
    for (int i = threadIdx.x; i < M; i += 1024) {
        double x = (double)nnd[i];
        s1 += x; s2 += x * x;
    }
    #pragma unroll
    for (int o = 32; o; o >>= 1) {
        s1 += __shfl_down(s1, o, 64);
        s2 += __shfl_down(s2, o, 64);
    }
    __shared__ double a1[16], a2[16];
    int wv = threadIdx.x >> 6, ln = threadIdx.x & 63;
    if (ln == 0) { a1[wv] = s1; a2[wv] = s2; }
    __syncthreads();
    if (threadIdx.x == 0) {
        double S1 = 0.0, S2 = 0.0;
        for (int i = 0; i < 16; ++i) { S1 += a1[i]; S2 += a2[i]; }
        double mean = S1 / M;
        double var  = (S2 - S1 * S1 / M) / (M - 1);
        double stdv = var > 0.0 ? sqrt(var) : 0.0;
        double cv   = (mean > 1e-8) ? stdv / fmax(mean, 1e-8) : 0.0;
        out[0] = (float)mean;
        out[1] = (float)stdv;
        out[2] = (float)cv;
    }
}

extern "C" void kernel_launch(void* const* d_in, const int* in_sizes, int n_in,
                              void* d_out, int out_size, void* d_ws, size_t ws_size,
                              hipStream_t stream) {
    const float* X = (const float*)d_in[0];
    unsigned short* Xs  = (unsigned short*)d_ws;                       // 8 MB bf16 swizzled
    float*          sqn = (float*)((char*)d_ws + (size_t)B_ * N_ * D_ * 2);
    float*          nnd = sqn + B_ * N_;
    float*          out = (float*)d_out;

    prep_kernel<<<B_ * N_ / 4, 256, 0, stream>>>(X, Xs, sqn);
    nnd_kernel<<<B_ * NT, 256, 0, stream>>>(Xs, sqn, nnd);
    finalize_kernel<<<1, 1024, 0, stream>>>(nnd, out);
}

// Round 2
// 42.646 us; speedup vs baseline: 1.0960x; 1.0960x over previous
//
#include <hip/hip_runtime.h>
#include <math.h>

// Problem constants (reference is fixed-shape).
#define B_ 16
#define N_ 2048
#define D_ 128

typedef __attribute__((ext_vector_type(8))) short bf16x8;   // 8 bf16 = 4 VGPRs
typedef __attribute__((ext_vector_type(4))) float f32x4;

__device__ __forceinline__ unsigned short f2bf(float f) {
    // round-to-nearest-even fp32 -> bf16 (inputs are finite Gaussians)
    unsigned u = __float_as_uint(f);
    u += 0x7FFFu + ((u >> 16) & 1u);
    return (unsigned short)(u >> 16);
}

// ---------------------------------------------------------------------------
// K1: fp32 -> bf16 (pre-swizzled layout) + fp32 squared norms + atomicMin-key
// init (must be re-done EVERY call: harness does not re-poison between replays).
// Swizzle: element d of row r stored at d ^ ((r&7)<<3) so a linear
// global->LDS copy gives a conflict-free layout when read with the same XOR.
// ---------------------------------------------------------------------------
__global__ __launch_bounds__(256) void prep_kernel(
        const float* __restrict__ X, unsigned short* __restrict__ Xs,
        float* __restrict__ sqn, unsigned* __restrict__ pmk) {
    int row = blockIdx.x * 4 + (threadIdx.x >> 6);
    int ln  = threadIdx.x & 63;
    const float* src = X + (size_t)row * D_;
    float2 v = *(const float2*)(src + ln * 2);
    unsigned short h0 = f2bf(v.x), h1 = f2bf(v.y);
    float f0 = __uint_as_float((unsigned)h0 << 16);
    float f1 = __uint_as_float((unsigned)h1 << 16);
    float s = f0 * f0 + f1 * f1;
    #pragma unroll
    for (int o = 32; o; o >>= 1) s += __shfl_xor(s, o, 64);
    int dsw = (ln * 2) ^ ((row & 7) << 3);   // XOR touches bits>=3; pair intact
    unsigned pack = (unsigned)h0 | ((unsigned)h1 << 16);
    *(unsigned*)(Xs + (size_t)row * D_ + dsw) = pack;
    if (ln == 0) { sqn[row] = s; pmk[row] = 0xFFFFFFFFu; }
}

// ---------------------------------------------------------------------------
// K2: fused Gram + row-min.  Grid 256 = B(16) x it(4: 512-row i-tiles) x
// jh(4: 4 j-tiles of 128).  8 waves x 64 rows/wave; A-frags in registers for
// the whole sweep; Xj double-buffered in LDS via linear global_load_lds of the
// pre-swizzled layout.  Row partial-min combined via uint-encoded atomicMin.
// ---------------------------------------------------------------------------
__device__ __forceinline__ void stage_tile(const unsigned short* gsrc,
                                           unsigned short* lds, int wv, int ln) {
    // 32 KB tile, 8 waves: each wave copies 4 KB = 4 x (64 lanes x 16 B).
    const char* g = (const char*)gsrc + wv * 4096 + ln * 16;
    char*       l = (char*)lds + wv * 4096;          // wave-uniform LDS base
    #pragma unroll
    for (int i = 0; i < 4; ++i) {
        __builtin_amdgcn_global_load_lds(
            (const __attribute__((address_space(1))) unsigned int*)(g + i * 1024),
            (__attribute__((address_space(3))) unsigned int*)(l + i * 1024),
            16, 0, 0);
    }
}

__global__ __launch_bounds__(512, 2) void nnd_kernel(
        const unsigned short* __restrict__ Xs, const float* __restrict__ sqn,
        unsigned* __restrict__ pmk) {
    __shared__ unsigned short Xj[2][128 * D_];   // 2 x 32 KB

    // XCD-chunked remap: 32 consecutive ids per XCD -> 2 batches per XCD L2.
    int wg  = (int)blockIdx.x;
    int id  = (wg & 7) * 32 + (wg >> 3);
    int b   = id >> 4;
    int sub = id & 15;
    int it  = sub >> 2;          // 512-row i-tile
    int jh  = sub & 3;           // j quarter (4 tiles of 128)

    int tid = threadIdx.x, wv = tid >> 6, ln = tid & 63;
    const unsigned short* Xb  = Xs  + (size_t)b * N_ * D_;
    const float*          sqb = sqn + b * N_;

    int rowbase = it * 512 + wv * 64;   // this wave's first row (within batch)
    int lr = ln & 15;                   // fragment row/col lane index
    int kg = (ln >> 4) * 8;             // A/B fragment k-group offset
    int rg = (ln >> 4) * 4;             // C/D fragment row-group offset

    // A fragments: 64 rows x K=128, in registers for the whole sweep.
    bf16x8 Af[4][4];
    #pragma unroll
    for (int m = 0; m < 4; ++m) {
        int r  = rowbase + m * 16 + lr;
        const unsigned short* rp = Xb + (size_t)r * D_;
        int sw = (r & 7) << 3;
        #pragma unroll
        for (int ks = 0; ks < 4; ++ks)
            Af[m][ks] = *(const bf16x8*)(rp + ((ks * 32 + kg) ^ sw));
    }

    float rmin[16];
    #pragma unroll
    for (int q = 0; q < 16; ++q) rmin[q] = 1e30f;
    const f32x4 zero4 = {0.f, 0.f, 0.f, 0.f};

    stage_tile(Xb + (size_t)(jh * 4) * 128 * D_, Xj[0], wv, ln);
    __syncthreads();

    for (int t = 0; t < 4; ++t) {
        int jt = jh * 4 + t, cur = t & 1;
        if (t < 3)
            stage_tile(Xb + (size_t)(jt + 1) * 128 * D_, Xj[cur ^ 1], wv, ln);

        const unsigned short* L = &Xj[cur][0];
        bool diag = (jt >> 2) == it;     // j-tile lies inside the i-range

        #pragma unroll
        for (int nh = 0; nh < 2; ++nh) {
            float nj[4];
            #pragma unroll
            for (int n = 0; n < 4; ++n)
                nj[n] = sqb[jt * 128 + nh * 64 + n * 16 + lr];

            f32x4 acc[4][4];
            #pragma unroll
            for (int ks = 0; ks < 4; ++ks) {
                bf16x8 Bf[4];
                #pragma unroll
                for (int n = 0; n < 4; ++n) {
                    int c = nh * 64 + n * 16 + lr;
                    Bf[n] = *(const bf16x8*)(L + c * D_ +
                                             ((ks * 32 + kg) ^ ((c & 7) << 3)));
                }
                #pragma unroll
                for (int m = 0; m < 4; ++m)
                    #pragma unroll
                    for (int n = 0; n < 4; ++n)
                        acc[m][n] = __builtin_amdgcn_mfma_f32_16x16x32_bf16(
                            Af[m][ks], Bf[n], ks ? acc[m][n] : zero4, 0, 0, 0);
            }

            // Fold min_j (n_j - 2 g).  C/D: col = lane&15, row = rg + reg.
            if (!diag) {
                #pragma unroll
                for (int m = 0; m < 4; ++m)
                    #pragma unroll
                    for (int rr = 0; rr < 4; ++rr) {
                        float t0 = fmaf(-2.f, acc[m][0][rr], nj[0]);
                        float t1 = fmaf(-2.f, acc[m][1][rr], nj[1]);
                        float t2 = fmaf(-2.f, acc[m][2][rr], nj[2]);
                        float t3 = fmaf(-2.f, acc[m][3][rr], nj[3]);
                        float m1 = fminf(fminf(t0, t1), t2);       // v_min3
                        rmin[m * 4 + rr] =
                            fminf(fminf(rmin[m * 4 + rr], m1), t3); // v_min3
                    }
            } else {
                #pragma unroll
                for (int m = 0; m < 4; ++m)
                    #pragma unroll
                    for (int rr = 0; rr < 4; ++rr) {
                        int ir = rowbase + m * 16 + rg + rr;
                        int jc = jt * 128 + nh * 64 + lr;
                        float t0 = (ir == jc)      ? 1e30f
                                   : fmaf(-2.f, acc[m][0][rr], nj[0]);
                        float t1 = (ir == jc + 16) ? 1e30f
                                   : fmaf(-2.f, acc[m][1][rr], nj[1]);
                        float t2 = (ir == jc + 32) ? 1e30f
                                   : fmaf(-2.f, acc[m][2][rr], nj[2]);
                        float t3 = (ir == jc + 48) ? 1e30f
                                   : fmaf(-2.f, acc[m][3][rr], nj[3]);
                        float m1 = fminf(fminf(t0, t1), t2);
                        rmin[m * 4 + rr] =
                            fminf(fminf(rmin[m * 4 + rr], m1), t3);
                    }
            }
        }
        __syncthreads();
    }

    // Min across the 16 column-lanes of each row group.
    #pragma unroll
    for (int o = 1; o < 16; o <<= 1)
        #pragma unroll
        for (int q = 0; q < 16; ++q)
            rmin[q] = fminf(rmin[q], __shfl_xor(rmin[q], o, 64));

    if (lr == 0) {
        #pragma unroll
        for (int m = 0; m < 4; ++m)
            #pragma unroll
            for (int rr = 0; rr < 4; ++rr) {
                int row = rowbase + m * 16 + rg + rr;
                float f = rmin[m * 4 + rr];
                unsigned u   = __float_as_uint(f);
                unsigned key = u ^ ((unsigned)((int)u >> 31) | 0x80000000u);
                atomicMin(pmk + b * N_ + row, key);   // exact, order-independent
            }
    }
}

// ---------------------------------------------------------------------------
// K3: decode keys -> nnd, then mean / unbiased std / CV in double.
// ---------------------------------------------------------------------------
__global__ __launch_bounds__(1024) void finalize_kernel(
        const unsigned* __restrict__ pmk, const float* __restrict__ sqn,
        float* __restrict__ out) {
    const int M = B_ * N_;
    double s1 = 0.0, s2 = 0.0;
    for (int i = threadIdx.x; i < M; i += 1024) {
        unsigned key = pmk[i];
        unsigned u   = (key & 0x80000000u) ? (key ^ 0x80000000u) : ~key;
        float rm = __uint_as_float(u);
        float d2 = sqn[i] + rm;
        double x = sqrt((double)fmaxf(d2, 0.f));
        s1 += x; s2 += x * x;
    }
    #pragma unroll
    for (int o = 32; o; o >>= 1) {
        s1 += __shfl_down(s1, o, 64);
        s2 += __shfl_down(s2, o, 64);
    }
    __shared__ double a1[16], a2[16];
    int wv = threadIdx.x >> 6, ln = threadIdx.x & 63;
    if (ln == 0) { a1[wv] = s1; a2[wv] = s2; }
    __syncthreads();
    if (threadIdx.x == 0) {
        double S1 = 0.0, S2 = 0.0;
        for (int i = 0; i < 16; ++i) { S1 += a1[i]; S2 += a2[i]; }
        double mean = S1 / M;
        double var  = (S2 - S1 * S1 / M) / (M - 1);
        double stdv = var > 0.0 ? sqrt(var) : 0.0;
        double cv   = (mean > 1e-8) ? stdv / fmax(mean, 1e-8) : 0.0;
        out[0] = (float)mean;
        out[1] = (float)stdv;
        out[2] = (float)cv;
    }
}

extern "C" void kernel_launch(void* const* d_in, const int* in_sizes, int n_in,
                              void* d_out, int out_size, void* d_ws, size_t ws_size,
                              hipStream_t stream) {
    const float* X = (const float*)d_in[0];
    const size_t XS_BYTES = (size_t)B_ * N_ * D_ * 2;        // 8 MB
    unsigned short* Xs  = (unsigned short*)d_ws;
    float*          sqn = (float*)((char*)d_ws + XS_BYTES);
    unsigned*       pmk = (unsigned*)((char*)d_ws + XS_BYTES + (size_t)B_ * N_ * 4);
    float*          out = (float*)d_out;

    prep_kernel<<<B_ * N_ / 4, 256, 0, stream>>>(X, Xs, sqn, pmk);
    nnd_kernel<<<256, 512, 0, stream>>>(Xs, sqn, pmk);
    finalize_kernel<<<1, 1024, 0, stream>>>(pmk, sqn, out);
}

// Round 3
// 41.586 us; speedup vs baseline: 1.1239x; 1.0255x over previous
//
#include <hip/hip_runtime.h>
#include <math.h>

// Problem constants (reference is fixed-shape).
#define B_ 16
#define N_ 2048
#define D_ 128

typedef __attribute__((ext_vector_type(8))) short bf16x8;   // 8 bf16 = 4 VGPRs
typedef __attribute__((ext_vector_type(4))) float f32x4;

__device__ __forceinline__ unsigned short f2bf(float f) {
    unsigned u = __float_as_uint(f);
    u += 0x7FFFu + ((u >> 16) & 1u);
    return (unsigned short)(u >> 16);
}

__device__ __forceinline__ unsigned minkey(float f) {
    // order-preserving uint encoding of float (for atomicMin): exact, assoc.
    unsigned u = __float_as_uint(f);
    return u ^ ((unsigned)((int)u >> 31) | 0x80000000u);
}

// ---------------------------------------------------------------------------
// K1: fp32 -> bf16 (pre-swizzled) + fp32 squared norms + per-call re-init of
// pmk keys and the finalize counter (harness does not re-poison between
// replays, so ALL state must be rebuilt every call).
// Swizzle: element d of row r stored at d ^ ((r&7)<<3): a linear global->LDS
// copy then gives conflict-free ds_read_b128 when read with the same XOR.
// ---------------------------------------------------------------------------
__global__ __launch_bounds__(256) void prep_kernel(
        const float* __restrict__ X, unsigned short* __restrict__ Xs,
        float* __restrict__ sqn, unsigned* __restrict__ pmk,
        unsigned* __restrict__ fincnt) {
    int row = blockIdx.x * 4 + (threadIdx.x >> 6);
    int ln  = threadIdx.x & 63;
    const float* src = X + (size_t)row * D_;
    float2 v = *(const float2*)(src + ln * 2);
    unsigned short h0 = f2bf(v.x), h1 = f2bf(v.y);
    float f0 = __uint_as_float((unsigned)h0 << 16);
    float f1 = __uint_as_float((unsigned)h1 << 16);
    float s = f0 * f0 + f1 * f1;
    #pragma unroll
    for (int o = 32; o; o >>= 1) s += __shfl_xor(s, o, 64);
    int dsw = (ln * 2) ^ ((row & 7) << 3);
    *(unsigned*)(Xs + (size_t)row * D_ + dsw) =
        (unsigned)h0 | ((unsigned)h1 << 16);
    if (ln == 0) { sqn[row] = s; pmk[row] = 0xFFFFFFFFu; }
    if (blockIdx.x == 0 && threadIdx.x == 0) *fincnt = 0u;
}

// ---------------------------------------------------------------------------
// K2: symmetric fused Gram + min.  576 WGs = 16 batches x 36 upper-triangle
// pairs of 256-row tiles (it<=jt).  8 waves x 32 i-rows each; j-block (256
// rows) staged once into 64 KB LDS via linear global_load_lds of the
// pre-swizzled layout.  Off-diagonal blocks fold BOTH row-mins (into pmk[i])
// and col-mins (into pmk[j]); diagonal blocks mask i==j by index and skip the
// col side (block is symmetric).  Partials merge via uint-keyed atomicMin
// (exact float min, order-independent -> deterministic).
// ---------------------------------------------------------------------------
__global__ __launch_bounds__(512, 2) void nnd_kernel(
        const unsigned short* __restrict__ Xs, const float* __restrict__ sqn,
        unsigned* __restrict__ pmk) {
    __shared__ unsigned short Xj[256 * D_];   // 64 KB j-block
    __shared__ float cs[8][256];              // 8 KB col-min cross-wave scratch

    // XCD-chunked remap (576 = 8 x 72, bijective): 72 consecutive ids per XCD
    // -> 2 batches per XCD L2.
    int wg = (int)blockIdx.x;
    int id = (wg & 7) * 72 + (wg >> 3);
    int b  = id / 36;
    int p  = id % 36;
    int it = 0;
    { int q = p; while (q >= 8 - it) { q -= 8 - it; ++it; } p = q; }
    int jt = it + p;
    bool diag = (it == jt);

    int tid = threadIdx.x, wv = tid >> 6, ln = tid & 63;
    int lr = ln & 15;                 // fragment row/col lane index
    int kg = (ln >> 4) * 8;           // A/B fragment k-group offset
    int rg = (ln >> 4) * 4;           // C/D fragment row-group offset

    const unsigned short* Xb  = Xs  + (size_t)b * N_ * D_;
    const float*          sqb = sqn + b * N_;
    int ibase = it * 256, jbase = jt * 256;

    // Stage j-block: 64 KB linear copy, 8 waves x 8 x (64 lanes x 16 B).
    {
        const char* g = (const char*)(Xb + (size_t)jbase * D_) + wv * 8192 + ln * 16;
        char*       l = (char*)Xj + wv * 8192;
        #pragma unroll
        for (int i = 0; i < 8; ++i)
            __builtin_amdgcn_global_load_lds(
                (const __attribute__((address_space(1))) unsigned int*)(g + i * 1024),
                (__attribute__((address_space(3))) unsigned int*)(l + i * 1024),
                16, 0, 0);
    }

    // A fragments: this wave's 32 i-rows x K=128, registers for whole block.
    bf16x8 Af[2][4];
    #pragma unroll
    for (int m = 0; m < 2; ++m) {
        int r  = ibase + wv * 32 + m * 16 + lr;
        const unsigned short* rp = Xb + (size_t)r * D_;
        int sw = (r & 7) << 3;
        #pragma unroll
        for (int ks = 0; ks < 4; ++ks)
            Af[m][ks] = *(const bf16x8*)(rp + ((ks * 32 + kg) ^ sw));
    }

    float ni[2][4];
    #pragma unroll
    for (int m = 0; m < 2; ++m)
        #pragma unroll
        for (int rr = 0; rr < 4; ++rr)
            ni[m][rr] = sqb[ibase + wv * 32 + m * 16 + rg + rr];

    float rmin[8];
    #pragma unroll
    for (int q = 0; q < 8; ++q) rmin[q] = 1e30f;
    const f32x4 zero4 = {0.f, 0.f, 0.f, 0.f};

    __syncthreads();   // staging complete (compiler drains vmcnt before barrier)

    #pragma unroll
    for (int nh = 0; nh < 2; ++nh) {
        float nj[8];
        #pragma unroll
        for (int n = 0; n < 8; ++n)
            nj[n] = sqb[jbase + nh * 128 + n * 16 + lr];

        f32x4 acc[2][8];
        #pragma unroll
        for (int ks = 0; ks < 4; ++ks) {
            bf16x8 Bf[8];
            #pragma unroll
            for (int n = 0; n < 8; ++n) {
                int c = nh * 128 + n * 16 + lr;
                Bf[n] = *(const bf16x8*)(&Xj[c * D_ +
                                             ((ks * 32 + kg) ^ ((c & 7) << 3))]);
            }
            #pragma unroll
            for (int m = 0; m < 2; ++m)
                #pragma unroll
                for (int n = 0; n < 8; ++n)
                    acc[m][n] = __builtin_amdgcn_mfma_f32_16x16x32_bf16(
                        Af[m][ks], Bf[n], ks ? acc[m][n] : zero4, 0, 0, 0);
        }

        // Epilogue.  C/D layout: col = lane&15, row = rg + reg  [m89/m91].
        if (!diag) {
            float cmin[8];
            #pragma unroll
            for (int n = 0; n < 8; ++n) cmin[n] = 1e30f;
            #pragma unroll
            for (int m = 0; m < 2; ++m)
                #pragma unroll
                for (int rr = 0; rr < 4; ++rr) {
                    float t[8];
                    #pragma unroll
                    for (int n = 0; n < 8; ++n)
                        t[n] = fmaf(-2.f, acc[m][n][rr], nj[n]);
                    float u0 = fminf(t[0], t[1]), u1 = fminf(t[2], t[3]);
                    float u2 = fminf(t[4], t[5]), u3 = fminf(t[6], t[7]);
                    rmin[m * 4 + rr] = fminf(rmin[m * 4 + rr],
                                             fminf(fminf(u0, u1), fminf(u2, u3)));
                    float nim = ni[m][rr];
                    #pragma unroll
                    for (int n = 0; n < 8; ++n)
                        cmin[n] = fminf(cmin[n],
                                        fmaf(-2.f, acc[m][n][rr], nim));
                }
            // col-min: reduce the 4 lane-groups sharing a column, stash in LDS.
            #pragma unroll
            for (int n = 0; n < 8; ++n) {
                float c = cmin[n];
                c = fminf(c, __shfl_xor(c, 16, 64));
                c = fminf(c, __shfl_xor(c, 32, 64));
                if (ln < 16) cs[wv][nh * 128 + n * 16 + ln] = c;
            }
        } else {
            #pragma unroll
            for (int m = 0; m < 2; ++m)
                #pragma unroll
                for (int rr = 0; rr < 4; ++rr) {
                    int ir = ibase + wv * 32 + m * 16 + rg + rr;
                    float t[8];
                    #pragma unroll
                    for (int n = 0; n < 8; ++n) {
                        int jc = jbase + nh * 128 + n * 16 + lr;
                        t[n] = (ir == jc) ? 1e30f
                                          : fmaf(-2.f, acc[m][n][rr], nj[n]);
                    }
                    float u0 = fminf(t[0], t[1]), u1 = fminf(t[2], t[3]);
                    float u2 = fminf(t[4], t[5]), u3 = fminf(t[6], t[7]);
                    rmin[m * 4 + rr] = fminf(rmin[m * 4 + rr],
                                             fminf(fminf(u0, u1), fminf(u2, u3)));
                }
        }
    }

    // Row-side: min across the 16 column-lanes, then one atomic per row.
    #pragma unroll
    for (int o = 1; o < 16; o <<= 1)
        #pragma unroll
        for (int q = 0; q < 8; ++q)
            rmin[q] = fminf(rmin[q], __shfl_xor(rmin[q], o, 64));
    if (lr == 0) {
        #pragma unroll
        for (int m = 0; m < 2; ++m)
            #pragma unroll
            for (int rr = 0; rr < 4; ++rr) {
                int row = ibase + wv * 32 + m * 16 + rg + rr;
                atomicMin(pmk + b * N_ + row, minkey(rmin[m * 4 + rr]));
            }
    }

    // Col-side: cross-wave reduce in LDS, one atomic per column.
    if (!diag) {
        __syncthreads();
        if (tid < 256) {
            float c = cs[0][tid];
            #pragma unroll
            for (int w = 1; w < 8; ++w) c = fminf(c, cs[w][tid]);
            atomicMin(pmk + b * N_ + jbase + tid, minkey(c));
        }
    }
}

// ---------------------------------------------------------------------------
// K3: decode keys -> nnd; mean / unbiased std / CV.  64 WGs write fixed f64
// partial slots; the last-arriving WG (device-scope counter) sums the slots
// with agent-scope atomic loads (stale-L2-safe across graph replays).
// ---------------------------------------------------------------------------
__global__ __launch_bounds__(512) void finalize_kernel(
        const unsigned* __restrict__ pmk, const float* __restrict__ sqn,
        double* __restrict__ slots, unsigned* __restrict__ fincnt,
        float* __restrict__ out) {
    const int M = B_ * N_;
    int r = blockIdx.x * 512 + (int)threadIdx.x;
    unsigned key = pmk[r];
    unsigned u   = (key & 0x80000000u) ? (key ^ 0x80000000u) : ~key;
    float d2 = sqn[r] + __uint_as_float(u);
    float x32 = sqrtf(fmaxf(d2, 0.f));       // reference uses f32 sqrt too
    double x = (double)x32;
    double s1 = x, s2 = x * x;
    #pragma unroll
    for (int o = 32; o; o >>= 1) {
        s1 += __shfl_down(s1, o, 64);
        s2 += __shfl_down(s2, o, 64);
    }
    __shared__ double a1[8], a2[8];
    int wv = threadIdx.x >> 6, ln = threadIdx.x & 63;
    if (ln == 0) { a1[wv] = s1; a2[wv] = s2; }
    __syncthreads();
    if (threadIdx.x == 0) {
        double S1 = 0.0, S2 = 0.0;
        #pragma unroll
        for (int w = 0; w < 8; ++w) { S1 += a1[w]; S2 += a2[w]; }
        slots[blockIdx.x * 2]     = S1;
        slots[blockIdx.x * 2 + 1] = S2;
        __threadfence();
        unsigned old = atomicAdd(fincnt, 1u);
        if (old == 63u) {
            double T1 = 0.0, T2 = 0.0;
            for (int w = 0; w < 64; ++w) {
                T1 += __hip_atomic_load(&slots[w * 2],     __ATOMIC_RELAXED,
                                        __HIP_MEMORY_SCOPE_AGENT);
                T2 += __hip_atomic_load(&slots[w * 2 + 1], __ATOMIC_RELAXED,
                                        __HIP_MEMORY_SCOPE_AGENT);
            }
            double mean = T1 / M;
            double var  = (T2 - T1 * T1 / M) / (M - 1);
            double stdv = var > 0.0 ? sqrt(var) : 0.0;
            double cv   = (mean > 1e-8) ? stdv / fmax(mean, 1e-8) : 0.0;
            out[0] = (float)mean;
            out[1] = (float)stdv;
            out[2] = (float)cv;
        }
    }
}

extern "C" void kernel_launch(void* const* d_in, const int* in_sizes, int n_in,
                              void* d_out, int out_size, void* d_ws, size_t ws_size,
                              hipStream_t stream) {
    const float* X = (const float*)d_in[0];
    const size_t XS_BYTES = (size_t)B_ * N_ * D_ * 2;        // 8 MB
    char* ws = (char*)d_ws;
    unsigned short* Xs     = (unsigned short*)ws;
    float*          sqn    = (float*)(ws + XS_BYTES);
    unsigned*       pmk    = (unsigned*)(ws + XS_BYTES + (size_t)B_ * N_ * 4);
    double*         slots  = (double*)(ws + XS_BYTES + (size_t)B_ * N_ * 8);
    unsigned*       fincnt = (unsigned*)(ws + XS_BYTES + (size_t)B_ * N_ * 8 + 1024);
    float*          out    = (float*)d_out;

    prep_kernel<<<B_ * N_ / 4, 256, 0, stream>>>(X, Xs, sqn, pmk, fincnt);
    nnd_kernel<<<16 * 36, 512, 0, stream>>>(Xs, sqn, pmk);
    finalize_kernel<<<B_ * N_ / 512, 512, 0, stream>>>(pmk, sqn, slots, fincnt, out);
}